// Round 28
// baseline (139.466 us; speedup 1.0000x reference)
//
#include <hip/hip_runtime.h>
#include <hip/hip_bf16.h>

typedef __attribute__((ext_vector_type(8))) short bf16x8;
typedef __attribute__((ext_vector_type(4))) float f32x4;

#define NCOLP 384                 // padded columns (352 real + 32 zero)
#define STEP_SHORTS (NCOLP * 32)  // 12288 shorts = 24576 B per 32-k step
#define STEP_BYTES 24576
#define SEG_BYTES 6144            // Wpack per-ablk segment: 384 cols * 8k * 2B
#define NSTEP 32
#define BROWS 65536
#define QSZF 65536                // quarter tile fp32: 64 rows x 1 KB

static __device__ __forceinline__ unsigned int bf16rne(float f) {
  unsigned int u = __float_as_uint(f);
  return (u + 0x7FFFu + ((u >> 16) & 1u)) >> 16;
}
static __device__ __forceinline__ unsigned int pack2(float a, float b) {
  return bf16rne(a) | (bf16rne(b) << 16);
}
static __device__ __forceinline__ void gload16(const void* g, void* l) {
  __builtin_amdgcn_global_load_lds(
      (const __attribute__((address_space(1))) unsigned int*)g,
      (__attribute__((address_space(3))) unsigned int*)l, 16, 0, 0);
}

// Wpack layout: [step][ablk(4)][col(384)][k%8] (bf16), 24576 B/step.
// Column map: [0,100) task0 (e*10+h), [100,200) task1, [200,300) shared,
// [300,340) gates (t*20+g), [340,384) zero pad.
__global__ void ple_prep(const float* __restrict__ Ws, const float* __restrict__ bs,
                         const float* __restrict__ Wt, const float* __restrict__ bt,
                         const float* __restrict__ Wg, const float* __restrict__ bg,
                         unsigned short* __restrict__ Wpack, float* __restrict__ bias) {
  const int n = blockIdx.x;  // 0..383
  const int tid = threadIdx.x;
  const float* src = nullptr;
  int stride = 0;
  float bval = 0.f;
  if (n < 200) {
    int t = n / 100, m = n % 100, e = m / 10, h = m % 10;
    src = Wt + (size_t)(t * 10 + e) * 10240 + h;
    stride = 10;
    bval = bt[(t * 10 + e) * 10 + h];
  } else if (n < 300) {
    int m = n - 200, e = m / 10, h = m % 10;
    src = Ws + (size_t)e * 10240 + h;
    stride = 10;
    bval = bs[e * 10 + h];
  } else if (n < 340) {
    int m = n - 300, t = m / 20, g = m % 20;
    src = Wg + (size_t)t * 20480 + g;
    stride = 20;
    bval = bg[t * 20 + g];
  }
  for (int j = 0; j < 4; j++) {
    int k = tid + j * 256;
    float v = src ? src[(size_t)k * stride] : 0.f;
    Wpack[(size_t)(k >> 5) * STEP_SHORTS + ((k >> 3) & 3) * (NCOLP * 8) + n * 8 +
          (k & 7)] = (unsigned short)bf16rne(v);
  }
  if (tid == 0 && n < 352) bias[n] = bval;
}

// Main: 256 threads = 4 waves, 64 rows/block, 1024 blocks, 1 block/CU.
// ZERO-VGPR STAGING: A staged fp32 via global_load_lds (no registers, no
// cvt at stage) into 2x64KB quarter buffers; exactly 2 gloads issued per
// K-step (HBM-rate-matched in the vmem FIFO against the triple-banked
// lead-2 register-B stream). Quarter barrier = vmcnt(6)+s_barrier (forces
// all gloads, leaves last 6 B-loads in flight). Swizzle via pre-swizzled
// GLOBAL source + linear LDS dest (rule #21); frag read phys-seg =
// (ks*4+ablk)^(arow&7), cvt fp32->bf16 at read (~32cy/step). HBM-bound by
// construction; 1 wave/SIMD suffices. 4-way quarter stagger retained.
__global__ __launch_bounds__(256, 1) void ple_main(
    const float* __restrict__ x, const unsigned short* __restrict__ Wpack,
    const float* __restrict__ bias, const float* __restrict__ Wc,
    const float* __restrict__ bc, const float* __restrict__ Wv,
    const float* __restrict__ bv, float* __restrict__ out) {
  __shared__ __align__(16) char smem[2 * QSZF];  // 128 KB; z aliases front
  float* z = (float*)smem;

  const int tid = threadIdx.x;
  const int l = tid & 63, w = tid >> 6;  // wave w -> cols [w*96, w*96+96)
  const int arow = l & 15, ablk = l >> 4;
  const int rowbase = blockIdx.x * 64;
  const int q0 = (int)(blockIdx.x & 3);  // 4-way stagger start quarter

  const f32x4 fzero = {0.f, 0.f, 0.f, 0.f};
  f32x4 acc[4][6];
#pragma unroll
  for (int i = 0; i < 4; ++i)
#pragma unroll
    for (int j = 0; j < 6; ++j) acc[i][j] = fzero;

  // B fragment base (per-lane 16B from Wpack; k-order matches A frags).
  const char* bbase = (const char*)Wpack + ablk * SEG_BYTES +
                      (w * 96 + arow) * 16;
  bf16x8 b0[6], b1[6], b2[6];  // triple bank, static indexing only

  // A staging: chunk c = tid + j*256 (j=0..15): row = w + 4j, 16B-half
  // t16 = l. LDS dest LINEAR: buf + c*16. Global source PRE-SWIZZLED:
  // logical 32B-seg s_log = (l>>1) ^ ((row)&7); (row&7) = w (even j) or
  // w+4 (odd j). Frag read recovers via phys = s_log ^ (arow&7).
  const char* srcE = (const char*)x + (size_t)(rowbase + w) * 4096 +
                     (((l >> 1) ^ w) * 32) + ((l & 1) * 16);
  const char* srcO = (const char*)x + (size_t)(rowbase + w) * 4096 +
                     (((l >> 1) ^ (w + 4)) * 32) + ((l & 1) * 16);
  char* dstb = smem + tid * 16;

  // GL2(PPOS, J): stage row-pair J (rows w+8J, w+8J+4) of quarter-position
  // PPOS into buf[PPOS&1]. 2 gload_lds, zero VGPR.
#define GL2(PPOS, J)                                                           \
  {                                                                            \
    const int qp = (q0 + (PPOS)) & 3;                                          \
    const size_t so = (size_t)((PPOS)&1) * QSZF;                               \
    gload16(srcE + (size_t)(8 * (J)) * 4096 + qp * 1024,                       \
            dstb + so + (size_t)(2 * (J)) * 4096);                             \
    gload16(srcO + (size_t)(8 * (J) + 4) * 4096 + qp * 1024,                   \
            dstb + so + (size_t)(2 * (J) + 1) * 4096);                         \
  }
  // STEPX(I, BU, BP): consume bank BU (= position I, step (q0*8+I)&31),
  // prefetch position I+2 -> BP. A from buf[(I>>3)&1] (fp32, cvt on read).
#define STEPX(I, BU, BP)                                                       \
  {                                                                            \
    const int ipre = ((I) + 2 <= 31) ? (I) + 2 : 31;                           \
    const int kpre = (q0 * 8 + ipre) & 31;                                     \
    const char* bp = bbase + (size_t)kpre * STEP_BYTES;                        \
    _Pragma("unroll") for (int nt = 0; nt < 6; nt++)                           \
        BP[nt] = *(const bf16x8*)(bp + nt * 256);                              \
    _Pragma("unroll") for (int mf = 0; mf < 4; mf++) {                         \
      const int phys = (((I)&7) * 4 + ablk) ^ (arow & 7);                      \
      const char* ar = smem + (size_t)(((I) >> 3) & 1) * QSZF +                \
                       (mf * 16 + arow) * 1024 + phys * 32;                    \
      const float4 fa = *(const float4*)(ar);                                  \
      const float4 fb = *(const float4*)(ar + 16);                             \
      union { bf16x8 v; uint4 u; } A;                                          \
      A.u = make_uint4(pack2(fa.x, fa.y), pack2(fa.z, fa.w),                   \
                       pack2(fb.x, fb.y), pack2(fb.z, fb.w));                  \
      _Pragma("unroll") for (int nt = 0; nt < 6; nt++)                         \
          acc[mf][nt] = __builtin_amdgcn_mfma_f32_16x16x32_bf16(               \
              A.v, BU[nt], acc[mf][nt], 0, 0, 0);                              \
    }                                                                          \
  }
#define SB __builtin_amdgcn_sched_barrier(0);
#define QBAR6                                                                  \
  asm volatile("s_waitcnt vmcnt(6)" ::: "memory");                             \
  __builtin_amdgcn_s_barrier();

  // ---- prologue: 16 gloads (position 0 -> buf0), then B preloads; the
  // vmcnt(12) forces the gloads and leaves the 12 B-loads in flight.
  GL2(0, 0) GL2(0, 1) GL2(0, 2) GL2(0, 3)
  GL2(0, 4) GL2(0, 5) GL2(0, 6) GL2(0, 7)
  SB
#pragma unroll
  for (int nt = 0; nt < 6; nt++) {
    b0[nt] = *(const bf16x8*)(bbase + (size_t)((q0 * 8) & 31) * STEP_BYTES +
                              nt * 256);
    b1[nt] = *(const bf16x8*)(bbase +
                              (size_t)((q0 * 8 + 1) & 31) * STEP_BYTES +
                              nt * 256);
  }
  SB
  asm volatile("s_waitcnt vmcnt(12)" ::: "memory");
  __builtin_amdgcn_s_barrier();
  SB

  // ---- P0: compute buf0 (positions 0-7), stage position1 -> buf1 ----
  GL2(1, 0) SB STEPX(0, b0, b2) SB
  GL2(1, 1) SB STEPX(1, b1, b0) SB
  GL2(1, 2) SB STEPX(2, b2, b1) SB
  GL2(1, 3) SB STEPX(3, b0, b2) SB
  GL2(1, 4) SB STEPX(4, b1, b0) SB
  GL2(1, 5) SB STEPX(5, b2, b1) SB
  GL2(1, 6) SB STEPX(6, b0, b2) SB
  GL2(1, 7) SB STEPX(7, b1, b0) SB
  QBAR6 SB

  // ---- P1: compute buf1 (positions 8-15), stage position2 -> buf0 ----
  GL2(2, 0) SB STEPX(8, b2, b1) SB
  GL2(2, 1) SB STEPX(9, b0, b2) SB
  GL2(2, 2) SB STEPX(10, b1, b0) SB
  GL2(2, 3) SB STEPX(11, b2, b1) SB
  GL2(2, 4) SB STEPX(12, b0, b2) SB
  GL2(2, 5) SB STEPX(13, b1, b0) SB
  GL2(2, 6) SB STEPX(14, b2, b1) SB
  GL2(2, 7) SB STEPX(15, b0, b2) SB
  QBAR6 SB

  // ---- P2: compute buf0 (positions 16-23), stage position3 -> buf1 ----
  GL2(3, 0) SB STEPX(16, b1, b0) SB
  GL2(3, 1) SB STEPX(17, b2, b1) SB
  GL2(3, 2) SB STEPX(18, b0, b2) SB
  GL2(3, 3) SB STEPX(19, b1, b0) SB
  GL2(3, 4) SB STEPX(20, b2, b1) SB
  GL2(3, 5) SB STEPX(21, b0, b2) SB
  GL2(3, 6) SB STEPX(22, b1, b0) SB
  GL2(3, 7) SB STEPX(23, b2, b1) SB
  QBAR6 SB

  // ---- P3: compute buf1 (positions 24-31), no staging ----
  STEPX(24, b0, b2) STEPX(25, b1, b0) STEPX(26, b2, b1) STEPX(27, b0, b2)
  STEPX(28, b1, b0) STEPX(29, b2, b1) STEPX(30, b0, b2) STEPX(31, b1, b0)

#undef QBAR6
#undef SB
#undef STEPX
#undef GL2
  __syncthreads();

  // ---- epilogue: 2 phases of 32 rows; 4 threads per (task,row) item.
  // D layout: row=(l>>4)*4+reg, col=l&15.
#pragma unroll
  for (int p = 0; p < 2; p++) {
    __syncthreads();
#pragma unroll
    for (int q = 0; q < 2; q++) {
      const int mf = p * 2 + q;
#pragma unroll
      for (int nt = 0; nt < 6; nt++) {
        if (w == 3 && nt >= 4) continue;  // cols >= 352 are zero pad
#pragma unroll
        for (int r = 0; r < 4; r++)
          z[(q * 16 + ablk * 4 + r) * 357 + w * 96 + nt * 16 + arow] =
              acc[mf][nt][r];
      }
    }
    __syncthreads();
    {
      const int item = tid >> 2, sub = tid & 3;  // 64 items x 4 threads
      const int t = item >> 5, r = item & 31;
      const float* zr = &z[r * 357];
      float gl[5], m = -1e30f;
#pragma unroll
      for (int v = 0; v < 5; v++) {
        const int u = sub * 5 + v;
        gl[v] = zr[300 + t * 20 + u] + bias[300 + t * 20 + u];
        m = fmaxf(m, gl[v]);
      }
      m = fmaxf(m, __shfl_xor(m, 1));
      m = fmaxf(m, __shfl_xor(m, 2));
      const float* Wl = t ? Wv : Wc;
      float wl[10];
#pragma unroll
      for (int h = 0; h < 10; h++) wl[h] = Wl[h];
      float s = 0.f, accum = 0.f;
#pragma unroll
      for (int v = 0; v < 5; v++) {
        const int u = sub * 5 + v;
        const float pu = __expf(gl[v] - m);
        s += pu;
        const int cbase = (u < 10) ? (t * 100 + u * 10) : (200 + (u - 10) * 10);
        float d = 0.f;
#pragma unroll
        for (int h = 0; h < 10; h++)
          d += fmaxf(zr[cbase + h] + bias[cbase + h], 0.f) * wl[h];
        accum += pu * d;
      }
      s += __shfl_xor(s, 1);
      s += __shfl_xor(s, 2);
      accum += __shfl_xor(accum, 1);
      accum += __shfl_xor(accum, 2);
      if (sub == 0) {
        const float logit = (t ? bv[0] : bc[0]) + accum / s;
        out[(size_t)t * BROWS + rowbase + p * 32 + r] =
            1.f / (1.f + __expf(-logit));
      }
    }
  }
}

extern "C" void kernel_launch(void* const* d_in, const int* in_sizes, int n_in,
                              void* d_out, int out_size, void* d_ws, size_t ws_size,
                              hipStream_t stream) {
  const float* x = (const float*)d_in[0];
  const float* Ws = (const float*)d_in[3];
  const float* bs = (const float*)d_in[4];
  const float* Wt = (const float*)d_in[5];
  const float* bt = (const float*)d_in[6];
  const float* Wg = (const float*)d_in[7];
  const float* bg = (const float*)d_in[8];
  const float* Wc = (const float*)d_in[9];
  const float* bc = (const float*)d_in[10];
  const float* Wv = (const float*)d_in[11];
  const float* bv = (const float*)d_in[12];
  unsigned short* Wpack = (unsigned short*)d_ws;
  float* bias = (float*)((char*)d_ws + (size_t)NCOLP * 1024 * 2);
  float* out = (float*)d_out;

  hipLaunchKernelGGL(ple_prep, dim3(NCOLP), dim3(256), 0, stream, Ws, bs, Wt, bt,
                     Wg, bg, Wpack, bias);
  hipLaunchKernelGGL(ple_main, dim3(BROWS / 64), dim3(256), 0, stream, x, Wpack,
                     bias, Wc, bc, Wv, bv, out);
}

// Round 29
// 78.177 us; speedup vs baseline: 1.7840x; 1.7840x over previous
//
#include <hip/hip_runtime.h>
#include <hip/hip_bf16.h>

typedef __attribute__((ext_vector_type(8))) short bf16x8;
typedef __attribute__((ext_vector_type(4))) float f32x4;

#define NCOLP 384                 // padded columns (352 real + 32 zero)
#define STEP_SHORTS (NCOLP * 32)  // 12288 shorts = 24576 B per 32-k step
#define STEP_BYTES 24576
#define SEG_BYTES 6144            // Wpack per-ablk segment: 384 cols * 8k * 2B
#define NSTEP 32
#define BROWS 65536
#define QSZ 32768                 // quarter tile: 64 rows x 512 B bf16

static __device__ __forceinline__ unsigned int bf16rne(float f) {
  unsigned int u = __float_as_uint(f);
  return (u + 0x7FFFu + ((u >> 16) & 1u)) >> 16;
}
static __device__ __forceinline__ unsigned int pack2(float a, float b) {
  return bf16rne(a) | (bf16rne(b) << 16);
}

// Wpack layout: [step][ablk(4)][col(384)][k%8] (bf16), 24576 B/step.
// Column map: [0,100) task0 (e*10+h), [100,200) task1, [200,300) shared,
// [300,340) gates (t*20+g), [340,384) zero pad.
__global__ void ple_prep(const float* __restrict__ Ws, const float* __restrict__ bs,
                         const float* __restrict__ Wt, const float* __restrict__ bt,
                         const float* __restrict__ Wg, const float* __restrict__ bg,
                         unsigned short* __restrict__ Wpack, float* __restrict__ bias) {
  const int n = blockIdx.x;  // 0..383
  const int tid = threadIdx.x;
  const float* src = nullptr;
  int stride = 0;
  float bval = 0.f;
  if (n < 200) {
    int t = n / 100, m = n % 100, e = m / 10, h = m % 10;
    src = Wt + (size_t)(t * 10 + e) * 10240 + h;
    stride = 10;
    bval = bt[(t * 10 + e) * 10 + h];
  } else if (n < 300) {
    int m = n - 200, e = m / 10, h = m % 10;
    src = Ws + (size_t)e * 10240 + h;
    stride = 10;
    bval = bs[e * 10 + h];
  } else if (n < 340) {
    int m = n - 300, t = m / 20, g = m % 20;
    src = Wg + (size_t)t * 20480 + g;
    stride = 20;
    bval = bg[t * 20 + g];
  }
  for (int j = 0; j < 4; j++) {
    int k = tid + j * 256;
    float v = src ? src[(size_t)k * stride] : 0.f;
    Wpack[(size_t)(k >> 5) * STEP_SHORTS + ((k >> 3) & 3) * (NCOLP * 8) + n * 8 +
          (k & 7)] = (unsigned short)bf16rne(v);
  }
  if (tid == 0 && n < 352) bias[n] = bval;
}

// Main: 256 threads = 4 waves, 64 rows/block, 1024 blocks, 2 blocks/CU.
// R26 chassis (in-compute staging, double-buffered quarters, triple-bank
// lead-2 register B) + 4-WAY QUARTER STAGGER (q0 = blockIdx&3; K-sum
// commutes) for device-wide HBM stage decorrelation, and B preload
// hoisted BEFORE the prologue stage so its L2 latency hides under the
// 16-deep HBM burst. All indexing by processed position I: global step
// kk = (q0*8 + I) & 31; physical quarter = (q0 + P) & 3.
__global__ __launch_bounds__(256, 2) void ple_main(
    const float* __restrict__ x, const unsigned short* __restrict__ Wpack,
    const float* __restrict__ bias, const float* __restrict__ Wc,
    const float* __restrict__ bc, const float* __restrict__ Wv,
    const float* __restrict__ bv, float* __restrict__ out) {
  __shared__ __align__(16) char smem[2 * QSZ];  // z[32][357] aliases front
  float* z = (float*)smem;

  const int tid = threadIdx.x;
  const int l = tid & 63, w = tid >> 6;  // wave w -> cols [w*96, w*96+96)
  const int arow = l & 15, ablk = l >> 4;
  const int rowbase = blockIdx.x * 64;
  const int q0 = (int)(blockIdx.x & 3);  // 4-way stagger start quarter

  const f32x4 fzero = {0.f, 0.f, 0.f, 0.f};
  f32x4 acc[4][6];
#pragma unroll
  for (int i = 0; i < 4; ++i)
#pragma unroll
    for (int j = 0; j < 6; ++j) acc[i][j] = fzero;

  // B fragment base (per-lane 16B from Wpack; k-order matches A frags).
  const char* bbase = (const char*)Wpack + ablk * SEG_BYTES +
                      (w * 96 + arow) * 16;
  bf16x8 b0[6], b1[6], b2[6];  // triple bank, static indexing only

  // A staging: wave w covers rows w+4j (j=0..15); lane l = 16B fp32 seg l
  // of the staged quarter (64 lanes x 16B = 1KB/row/quarter, coalesced).
  const char* xstage = (const char*)x + (size_t)(rowbase + w) * 4096 + l * 16;
  float4 g[8], hgrp[8];

  // P = processed quarter position (0..3); physical quarter = (q0+P)&3.
#define GISSUE(P, G, J0)                                                       \
  {                                                                            \
    const int qp = (q0 + (P)) & 3;                                             \
    _Pragma("unroll") for (int j = 0; j < 8; j++)                              \
        G[j] = *(const float4*)(xstage + (size_t)((J0) + j) * 4 * 4096 +       \
                                qp * 1024);                                    \
  }
#define GWRITE(P, G, J0)                                                       \
  {                                                                            \
    _Pragma("unroll") for (int j = 0; j < 8; j++) {                            \
      const int row = w + ((J0) + j) * 4;                                      \
      const int s = l >> 1;                                                    \
      const int segp = (s & 24) | ((s & 7) ^ (row & 7));                       \
      uint2 u;                                                                 \
      u.x = pack2(G[j].x, G[j].y);                                             \
      u.y = pack2(G[j].z, G[j].w);                                             \
      *(uint2*)(smem + ((P)&1) * QSZ + row * 512 + segp * 16 + (l & 1) * 8) =  \
          u;                                                                   \
    }                                                                          \
  }
  // STEPX(I, BU, BP): consume bank BU (= position I, step (q0*8+I)&31),
  // prefetch position I+2 -> BP. A from buf[(I>>3)&1], seg s=(I&7)*4+ablk.
#define STEPX(I, BU, BP)                                                       \
  {                                                                            \
    const int ipre = ((I) + 2 <= 31) ? (I) + 2 : 31;                           \
    const int kpre = (q0 * 8 + ipre) & 31;                                     \
    const char* bp = bbase + (size_t)kpre * STEP_BYTES;                        \
    _Pragma("unroll") for (int nt = 0; nt < 6; nt++)                           \
        BP[nt] = *(const bf16x8*)(bp + nt * 256);                              \
    _Pragma("unroll") for (int mf = 0; mf < 4; mf++) {                         \
      const int s = ((I)&7) * 4 + ablk;                                        \
      const int segp = (s & 24) | ((s & 7) ^ (arow & 7));                      \
      const bf16x8 av =                                                        \
          *(const bf16x8*)(smem + (((I) >> 3) & 1) * QSZ +                     \
                           (mf * 16 + arow) * 512 + segp * 16);                \
      _Pragma("unroll") for (int nt = 0; nt < 6; nt++)                         \
          acc[mf][nt] = __builtin_amdgcn_mfma_f32_16x16x32_bf16(               \
              av, BU[nt], acc[mf][nt], 0, 0, 0);                               \
    }                                                                          \
  }
#define SB __builtin_amdgcn_sched_barrier(0);
#define QBAR                                                                   \
  asm volatile("s_waitcnt lgkmcnt(0)" ::: "memory");                           \
  __builtin_amdgcn_s_barrier();

  // ---- prologue: B preload (positions 0,1) issued FIRST, then stage
  // position 0 -> buf0 (depth-8 groups); B latency hides under the burst.
#pragma unroll
  for (int nt = 0; nt < 6; nt++) {
    b0[nt] = *(const bf16x8*)(bbase + (size_t)((q0 * 8) & 31) * STEP_BYTES +
                              nt * 256);
    b1[nt] = *(const bf16x8*)(bbase +
                              (size_t)((q0 * 8 + 1) & 31) * STEP_BYTES +
                              nt * 256);
  }
  SB
  GISSUE(0, g, 0) SB GWRITE(0, g, 0) SB GISSUE(0, hgrp, 8) SB
  GWRITE(0, hgrp, 8) QBAR SB

  // ---- P0: compute buf0 (positions 0-7), stage position1 -> buf1 ----
  STEPX(0, b0, b2) STEPX(1, b1, b0)
  SB GISSUE(1, g, 0) SB
  STEPX(2, b2, b1) STEPX(3, b0, b2) STEPX(4, b1, b0)
  SB GWRITE(1, g, 0) SB GISSUE(1, hgrp, 8) SB
  STEPX(5, b2, b1) STEPX(6, b0, b2) STEPX(7, b1, b0)
  SB GWRITE(1, hgrp, 8) QBAR SB

  // ---- P1: compute buf1 (positions 8-15), stage position2 -> buf0 ----
  STEPX(8, b2, b1) STEPX(9, b0, b2)
  SB GISSUE(2, g, 0) SB
  STEPX(10, b1, b0) STEPX(11, b2, b1) STEPX(12, b0, b2)
  SB GWRITE(2, g, 0) SB GISSUE(2, hgrp, 8) SB
  STEPX(13, b1, b0) STEPX(14, b2, b1) STEPX(15, b0, b2)
  SB GWRITE(2, hgrp, 8) QBAR SB

  // ---- P2: compute buf0 (positions 16-23), stage position3 -> buf1 ----
  STEPX(16, b1, b0) STEPX(17, b2, b1)
  SB GISSUE(3, g, 0) SB
  STEPX(18, b0, b2) STEPX(19, b1, b0) STEPX(20, b2, b1)
  SB GWRITE(3, g, 0) SB GISSUE(3, hgrp, 8) SB
  STEPX(21, b0, b2) STEPX(22, b1, b0) STEPX(23, b2, b1)
  SB GWRITE(3, hgrp, 8) QBAR SB

  // ---- P3: compute buf1 (positions 24-31), no staging ----
  STEPX(24, b0, b2) STEPX(25, b1, b0) STEPX(26, b2, b1) STEPX(27, b0, b2)
  STEPX(28, b1, b0) STEPX(29, b2, b1) STEPX(30, b0, b2) STEPX(31, b1, b0)
  QBAR

#undef QBAR
#undef SB
#undef STEPX
#undef GWRITE
#undef GISSUE

  // ---- epilogue: 2 phases of 32 rows; 4 threads per (task,row) item.
  // D layout: row=(l>>4)*4+reg, col=l&15.
#pragma unroll
  for (int p = 0; p < 2; p++) {
    __syncthreads();
#pragma unroll
    for (int q = 0; q < 2; q++) {
      const int mf = p * 2 + q;
#pragma unroll
      for (int nt = 0; nt < 6; nt++) {
        if (w == 3 && nt >= 4) continue;  // cols >= 352 are zero pad
#pragma unroll
        for (int r = 0; r < 4; r++)
          z[(q * 16 + ablk * 4 + r) * 357 + w * 96 + nt * 16 + arow] =
              acc[mf][nt][r];
      }
    }
    __syncthreads();
    {
      const int item = tid >> 2, sub = tid & 3;  // 64 items x 4 threads
      const int t = item >> 5, r = item & 31;
      const float* zr = &z[r * 357];
      float gl[5], m = -1e30f;
#pragma unroll
      for (int v = 0; v < 5; v++) {
        const int u = sub * 5 + v;
        gl[v] = zr[300 + t * 20 + u] + bias[300 + t * 20 + u];
        m = fmaxf(m, gl[v]);
      }
      m = fmaxf(m, __shfl_xor(m, 1));
      m = fmaxf(m, __shfl_xor(m, 2));
      const float* Wl = t ? Wv : Wc;
      float wl[10];
#pragma unroll
      for (int h = 0; h < 10; h++) wl[h] = Wl[h];
      float s = 0.f, accum = 0.f;
#pragma unroll
      for (int v = 0; v < 5; v++) {
        const int u = sub * 5 + v;
        const float pu = __expf(gl[v] - m);
        s += pu;
        const int cbase = (u < 10) ? (t * 100 + u * 10) : (200 + (u - 10) * 10);
        float d = 0.f;
#pragma unroll
        for (int h = 0; h < 10; h++)
          d += fmaxf(zr[cbase + h] + bias[cbase + h], 0.f) * wl[h];
        accum += pu * d;
      }
      s += __shfl_xor(s, 1);
      s += __shfl_xor(s, 2);
      accum += __shfl_xor(accum, 1);
      accum += __shfl_xor(accum, 2);
      if (sub == 0) {
        const float logit = (t ? bv[0] : bc[0]) + accum / s;
        out[(size_t)t * BROWS + rowbase + p * 32 + r] =
            1.f / (1.f + __expf(-logit));
      }
    }
  }
}

extern "C" void kernel_launch(void* const* d_in, const int* in_sizes, int n_in,
                              void* d_out, int out_size, void* d_ws, size_t ws_size,
                              hipStream_t stream) {
  const float* x = (const float*)d_in[0];
  const float* Ws = (const float*)d_in[3];
  const float* bs = (const float*)d_in[4];
  const float* Wt = (const float*)d_in[5];
  const float* bt = (const float*)d_in[6];
  const float* Wg = (const float*)d_in[7];
  const float* bg = (const float*)d_in[8];
  const float* Wc = (const float*)d_in[9];
  const float* bc = (const float*)d_in[10];
  const float* Wv = (const float*)d_in[11];
  const float* bv = (const float*)d_in[12];
  unsigned short* Wpack = (unsigned short*)d_ws;
  float* bias = (float*)((char*)d_ws + (size_t)NCOLP * 1024 * 2);
  float* out = (float*)d_out;

  hipLaunchKernelGGL(ple_prep, dim3(NCOLP), dim3(256), 0, stream, Ws, bs, Wt, bt,
                     Wg, bg, Wpack, bias);
  hipLaunchKernelGGL(ple_main, dim3(BROWS / 64), dim3(256), 0, stream, x, Wpack,
                     bias, Wc, bc, Wv, bv, out);
}